// Round 1
// baseline (677.808 us; speedup 1.0000x reference)
//
#include <hip/hip_runtime.h>
#include <hip/hip_bf16.h>

#define BSZ 4
#define NN 2048
#define HH 768
#define NHEAD 12
#define HD 64
#define DEG 16
#define NREL 64
#define MTOT (BSZ * NN)          // 8192 rows
#define ETOT (BSZ * NN * DEG)    // 131072 edges

// ---------------------------------------------------------------------------
// QKV projection: out[m,n] = sum_k X[m,k] * W[n,k] + b[n]   (torch Linear)
// Tile 64x64, BK=16, 256 threads, 4x4 acc per thread. f32 baseline.
// ---------------------------------------------------------------------------
__global__ __launch_bounds__(256) void qkv_gemm(
    const float* __restrict__ X,
    const float* __restrict__ Wq, const float* __restrict__ bq,
    const float* __restrict__ Wk, const float* __restrict__ bk,
    const float* __restrict__ Wv, const float* __restrict__ bv,
    float* __restrict__ Qo, float* __restrict__ Ko, float* __restrict__ Vo)
{
    const float* W; const float* bias; float* out;
    if (blockIdx.z == 0)      { W = Wq; bias = bq; out = Qo; }
    else if (blockIdx.z == 1) { W = Wk; bias = bk; out = Ko; }
    else                      { W = Wv; bias = bv; out = Vo; }

    // pad 17: compute-read banks spread (stride 17 ≡ conflict-free-ish)
    __shared__ float As[64][17];
    __shared__ float Bs[64][17];

    const int t  = threadIdx.x;
    const int tx = t & 15;        // n-group
    const int ty = t >> 4;        // m-group
    const int bm = blockIdx.y * 64;
    const int bn = blockIdx.x * 64;
    const int lrow = t >> 2;          // 0..63
    const int lcol = (t & 3) * 4;     // 0,4,8,12

    float acc[4][4] = {};

    for (int k0 = 0; k0 < HH; k0 += 16) {
        const float4 a4 = *(const float4*)(X + (size_t)(bm + lrow) * HH + k0 + lcol);
        const float4 b4 = *(const float4*)(W + (size_t)(bn + lrow) * HH + k0 + lcol);
        __syncthreads();   // previous iteration's reads done
        As[lrow][lcol + 0] = a4.x; As[lrow][lcol + 1] = a4.y;
        As[lrow][lcol + 2] = a4.z; As[lrow][lcol + 3] = a4.w;
        Bs[lrow][lcol + 0] = b4.x; Bs[lrow][lcol + 1] = b4.y;
        Bs[lrow][lcol + 2] = b4.z; Bs[lrow][lcol + 3] = b4.w;
        __syncthreads();

        #pragma unroll
        for (int kk = 0; kk < 16; ++kk) {
            float a[4], b[4];
            #pragma unroll
            for (int i = 0; i < 4; ++i) a[i] = As[ty * 4 + i][kk];
            #pragma unroll
            for (int j = 0; j < 4; ++j) b[j] = Bs[tx * 4 + j][kk];
            #pragma unroll
            for (int i = 0; i < 4; ++i)
                #pragma unroll
                for (int j = 0; j < 4; ++j)
                    acc[i][j] += a[i] * b[j];
        }
    }

    const float4 bias4 = *(const float4*)(bias + bn + tx * 4);
    #pragma unroll
    for (int i = 0; i < 4; ++i) {
        float4 o;
        o.x = acc[i][0] + bias4.x;
        o.y = acc[i][1] + bias4.y;
        o.z = acc[i][2] + bias4.z;
        o.w = acc[i][3] + bias4.w;
        *(float4*)(out + (size_t)(bm + ty * 4 + i) * HH + bn + tx * 4) = o;
    }
}

// ---------------------------------------------------------------------------
// Edge attention. One block per (b,dst) segment (edges are contiguous:
// e = seg*DEG + d by construction). One wave handles 3 heads.
// logits = Q·(K+Ek)/8; 16-way softmax in registers; out = sum attn*(V+Ev).
// ---------------------------------------------------------------------------
__global__ __launch_bounds__(256) void attn_kernel(
    const float* __restrict__ Q, const float* __restrict__ K,
    const float* __restrict__ V,
    const float* __restrict__ Ek, const float* __restrict__ Ev,
    const int* __restrict__ eidx, float* __restrict__ out)
{
    const int seg  = blockIdx.x;          // b*N + dst
    const int t    = threadIdx.x;
    const int lane = t & 63;
    const int wave = t >> 6;

    __shared__ int s_src[DEG];
    __shared__ int s_rel[DEG];
    if (t < DEG) {
        s_src[t] = eidx[2 * ETOT + seg * DEG + t];
        s_rel[t] = eidx[3 * ETOT + seg * DEG + t];
    }
    __syncthreads();

    const int b = seg >> 11;              // seg / N  (N = 2048)
    const float inv_scale = 0.125f;       // 1/sqrt(HD)

    float attn[3][DEG];

    #pragma unroll
    for (int hh = 0; hh < 3; ++hh) {
        const int h   = wave * 3 + hh;
        const int col = h * HD + lane;
        const float qv = Q[(size_t)seg * HH + col];
        #pragma unroll
        for (int d = 0; d < DEG; ++d) {
            const int src = s_src[d];
            const int rel = s_rel[d];
            const float kv = K[(size_t)(b * NN + src) * HH + col]
                           + Ek[(size_t)rel * HH + col];
            float p = qv * kv;
            #pragma unroll
            for (int m = 1; m < 64; m <<= 1) p += __shfl_xor(p, m, 64);
            attn[hh][d] = p * inv_scale;  // all lanes hold the full dot
        }
        // softmax over DEG (redundant in every lane; wave-uniform)
        float mx = attn[hh][0];
        #pragma unroll
        for (int d = 1; d < DEG; ++d) mx = fmaxf(mx, attn[hh][d]);
        float s = 0.f;
        #pragma unroll
        for (int d = 0; d < DEG; ++d) { attn[hh][d] = __expf(attn[hh][d] - mx); s += attn[hh][d]; }
        const float inv = 1.0f / s;
        #pragma unroll
        for (int d = 0; d < DEG; ++d) attn[hh][d] *= inv;
    }

    #pragma unroll
    for (int hh = 0; hh < 3; ++hh) {
        const int h   = wave * 3 + hh;
        const int col = h * HD + lane;
        float o = 0.f;
        #pragma unroll
        for (int d = 0; d < DEG; ++d) {
            const int src = s_src[d];
            const int rel = s_rel[d];
            o += attn[hh][d] * (V[(size_t)(b * NN + src) * HH + col]
                              + Ev[(size_t)rel * HH + col]);
        }
        out[(size_t)seg * HH + col] = o;
    }
}

// ---------------------------------------------------------------------------
extern "C" void kernel_launch(void* const* d_in, const int* in_sizes, int n_in,
                              void* d_out, int out_size, void* d_ws, size_t ws_size,
                              hipStream_t stream)
{
    const float* X  = (const float*)d_in[0];
    const int* eidx = (const int*)d_in[1];
    const float* Wq = (const float*)d_in[2];
    const float* bq = (const float*)d_in[3];
    const float* Wk = (const float*)d_in[4];
    const float* bk = (const float*)d_in[5];
    const float* Wv = (const float*)d_in[6];
    const float* bv = (const float*)d_in[7];
    const float* Ek = (const float*)d_in[8];
    const float* Ev = (const float*)d_in[9];
    float* out = (float*)d_out;

    float* Q = (float*)d_ws;
    float* K = Q + (size_t)MTOT * HH;
    float* V = K + (size_t)MTOT * HH;

    dim3 g1(HH / 64, MTOT / 64, 3);
    qkv_gemm<<<g1, 256, 0, stream>>>(X, Wq, bq, Wk, bk, Wv, bv, Q, K, V);

    attn_kernel<<<MTOT, 256, 0, stream>>>(Q, K, V, Ek, Ev, eidx, out);
}

// Round 2
// 188.359 us; speedup vs baseline: 3.5985x; 3.5985x over previous
//
#include <hip/hip_runtime.h>
#include <hip/hip_bf16.h>

#define BSZ 4
#define NN 2048
#define HH 768
#define NOUT 2304            // 3*HH (Q,K,V fused along N)
#define NHEAD 12
#define HD 64
#define DEG 16
#define MTOT (BSZ * NN)      // 8192
#define ETOT (MTOT * DEG)    // 131072

typedef __attribute__((ext_vector_type(4))) float f32x4;
typedef __attribute__((ext_vector_type(8))) short bf16x8;

__device__ __forceinline__ unsigned short f2bf(float f) {
    union { float f; unsigned int u; } v; v.f = f;
    unsigned int r = v.u + 0x7FFFu + ((v.u >> 16) & 1u);   // RNE
    return (unsigned short)(r >> 16);
}

__device__ __forceinline__ void gload16(const unsigned short* g, unsigned short* l) {
    __builtin_amdgcn_global_load_lds(
        (const __attribute__((address_space(1))) unsigned int*)g,
        (__attribute__((address_space(3))) unsigned int*)l,
        16, 0, 0);
}

// ---------------------------------------------------------------------------
// X (8192x768 f32) -> bf16.  6291456 elems = 3072 blocks * 256 thr * 8 elems.
// ---------------------------------------------------------------------------
__global__ __launch_bounds__(256) void convert_x(
    const float* __restrict__ X, unsigned short* __restrict__ Xb)
{
    const size_t i = ((size_t)blockIdx.x * 256 + threadIdx.x) * 8;
    const float4 a = *(const float4*)(X + i);
    const float4 b = *(const float4*)(X + i + 4);
    bf16x8 o;
    o[0] = f2bf(a.x); o[1] = f2bf(a.y); o[2] = f2bf(a.z); o[3] = f2bf(a.w);
    o[4] = f2bf(b.x); o[5] = f2bf(b.y); o[6] = f2bf(b.z); o[7] = f2bf(b.w);
    *(bf16x8*)(Xb + i) = o;
}

// ---------------------------------------------------------------------------
// Wq/Wk/Wv (each 768x768 f32) -> Wcat bf16 [2304][768]; biases -> bias_cat f32.
// 1769472 elems = 864 blocks * 256 thr * 8 elems.
// ---------------------------------------------------------------------------
__global__ __launch_bounds__(256) void convert_w(
    const float* __restrict__ Wq, const float* __restrict__ Wk,
    const float* __restrict__ Wv,
    const float* __restrict__ bq, const float* __restrict__ bk,
    const float* __restrict__ bv,
    unsigned short* __restrict__ Wb, float* __restrict__ biasb)
{
    const int tid = blockIdx.x * 256 + threadIdx.x;
    const size_t i = (size_t)tid * 8;
    const int row = (int)(i / HH);          // 0..2303
    const size_t off = i - (size_t)row * HH;
    const float* src = (row < HH) ? (Wq + (size_t)row * HH)
                     : (row < 2 * HH) ? (Wk + (size_t)(row - HH) * HH)
                                      : (Wv + (size_t)(row - 2 * HH) * HH);
    const float4 a = *(const float4*)(src + off);
    const float4 b = *(const float4*)(src + off + 4);
    bf16x8 o;
    o[0] = f2bf(a.x); o[1] = f2bf(a.y); o[2] = f2bf(a.z); o[3] = f2bf(a.w);
    o[4] = f2bf(b.x); o[5] = f2bf(b.y); o[6] = f2bf(b.z); o[7] = f2bf(b.w);
    *(bf16x8*)(Wb + i) = o;

    if (tid < NOUT) {
        biasb[tid] = (tid < HH) ? bq[tid]
                   : (tid < 2 * HH) ? bk[tid - HH] : bv[tid - 2 * HH];
    }
}

// ---------------------------------------------------------------------------
// Fused QKV GEMM: C[m, n] = Xb[m, :] . Wb[n, :] + bias[n],  m<8192, n<2304.
// m97 structure: 128x128 tile, BK=32, 4 waves (2x2), 4x4 16x16x32 bf16 MFMA
// per wave, global_load_lds width-16 staging, 2 barriers per K-step.
// ---------------------------------------------------------------------------
__global__ __launch_bounds__(256) void qkv_mfma(
    const unsigned short* __restrict__ Xb,   // [8192][768] bf16
    const unsigned short* __restrict__ Wb,   // [2304][768] bf16
    const float* __restrict__ biasb,         // [2304] f32
    float* __restrict__ Qo, float* __restrict__ Ko, float* __restrict__ Vo)
{
    __shared__ unsigned short As[128 * 32];
    __shared__ unsigned short Bs[128 * 32];

    const int t    = threadIdx.x;
    const int lane = t & 63;
    const int w    = t >> 6;          // wave 0..3
    const int wr   = w >> 1;          // wave row (2x2)
    const int wc   = w & 1;           // wave col
    const int bm   = blockIdx.y * 128;
    const int bn   = blockIdx.x * 128;

    // staging: per wave-issue, 64 lanes x 16B = 16 rows of 32 bf16
    const int srow = w * 16 + (lane >> 2);     // row within 64-row half
    const int schk = (lane & 3) * 8;           // k-element offset (16B chunks)

    const unsigned short* Asrc0 = Xb + (size_t)(bm + srow) * HH + schk;
    const unsigned short* Asrc1 = Asrc0 + (size_t)64 * HH;
    const unsigned short* Bsrc0 = Wb + (size_t)(bn + srow) * HH + schk;
    const unsigned short* Bsrc1 = Bsrc0 + (size_t)64 * HH;

    unsigned short* Adst0 = As + (w * 16) * 32;        // wave-uniform bases
    unsigned short* Adst1 = As + (64 + w * 16) * 32;
    unsigned short* Bdst0 = Bs + (w * 16) * 32;
    unsigned short* Bdst1 = Bs + (64 + w * 16) * 32;

    f32x4 acc[4][4];
    #pragma unroll
    for (int mi = 0; mi < 4; ++mi)
        #pragma unroll
        for (int ni = 0; ni < 4; ++ni)
            acc[mi][ni] = (f32x4){0.f, 0.f, 0.f, 0.f};

    const int fr = lane & 15;        // fragment row
    const int fk = (lane >> 4) * 8;  // fragment k-offset (elements)

    for (int k0 = 0; k0 < HH; k0 += 32) {
        __syncthreads();             // previous compute done before overwrite
        gload16(Asrc0 + k0, Adst0);
        gload16(Asrc1 + k0, Adst1);
        gload16(Bsrc0 + k0, Bdst0);
        gload16(Bsrc1 + k0, Bdst1);
        __syncthreads();             // compiler drains vmcnt before barrier

        bf16x8 a[4], b[4];
        #pragma unroll
        for (int mi = 0; mi < 4; ++mi)
            a[mi] = *(const bf16x8*)(As + (wr * 64 + mi * 16 + fr) * 32 + fk);
        #pragma unroll
        for (int ni = 0; ni < 4; ++ni)
            b[ni] = *(const bf16x8*)(Bs + (wc * 64 + ni * 16 + fr) * 32 + fk);
        #pragma unroll
        for (int mi = 0; mi < 4; ++mi)
            #pragma unroll
            for (int ni = 0; ni < 4; ++ni)
                acc[mi][ni] = __builtin_amdgcn_mfma_f32_16x16x32_bf16(
                    a[mi], b[ni], acc[mi][ni], 0, 0, 0);
    }

    // epilogue: bias + route N-tile to Q/K/V (each 128-tile within one array)
    float* outp; int ncol0;
    if (bn < HH)            { outp = Qo; ncol0 = bn; }
    else if (bn < 2 * HH)   { outp = Ko; ncol0 = bn - HH; }
    else                    { outp = Vo; ncol0 = bn - 2 * HH; }

    const int crow = (lane >> 4) * 4;    // C/D: row=(lane>>4)*4+reg
    const int ccol = lane & 15;          //      col=lane&15
    #pragma unroll
    for (int ni = 0; ni < 4; ++ni) {
        const int gcol = wc * 64 + ni * 16 + ccol;
        const float bias = biasb[bn + gcol];
        #pragma unroll
        for (int mi = 0; mi < 4; ++mi) {
            #pragma unroll
            for (int r = 0; r < 4; ++r) {
                const int grow = bm + wr * 64 + mi * 16 + crow + r;
                outp[(size_t)grow * HH + ncol0 + gcol] = acc[mi][ni][r] + bias;
            }
        }
    }
}

// ---------------------------------------------------------------------------
// Edge attention (unchanged from round 1). One block per (b,dst) segment;
// edges contiguous: e = seg*DEG + d. logits = Q.(K+Ek)/8; softmax over DEG.
// ---------------------------------------------------------------------------
__global__ __launch_bounds__(256) void attn_kernel(
    const float* __restrict__ Q, const float* __restrict__ K,
    const float* __restrict__ V,
    const float* __restrict__ Ek, const float* __restrict__ Ev,
    const int* __restrict__ eidx, float* __restrict__ out)
{
    const int seg  = blockIdx.x;          // b*N + dst
    const int t    = threadIdx.x;
    const int lane = t & 63;
    const int wave = t >> 6;

    __shared__ int s_src[DEG];
    __shared__ int s_rel[DEG];
    if (t < DEG) {
        s_src[t] = eidx[2 * ETOT + seg * DEG + t];
        s_rel[t] = eidx[3 * ETOT + seg * DEG + t];
    }
    __syncthreads();

    const int b = seg >> 11;              // seg / N
    const float inv_scale = 0.125f;

    float attn[3][DEG];

    #pragma unroll
    for (int hh = 0; hh < 3; ++hh) {
        const int h   = wave * 3 + hh;
        const int col = h * HD + lane;
        const float qv = Q[(size_t)seg * HH + col];
        #pragma unroll
        for (int d = 0; d < DEG; ++d) {
            const int src = s_src[d];
            const int rel = s_rel[d];
            const float kv = K[(size_t)(b * NN + src) * HH + col]
                           + Ek[(size_t)rel * HH + col];
            float p = qv * kv;
            #pragma unroll
            for (int m = 1; m < 64; m <<= 1) p += __shfl_xor(p, m, 64);
            attn[hh][d] = p * inv_scale;
        }
        float mx = attn[hh][0];
        #pragma unroll
        for (int d = 1; d < DEG; ++d) mx = fmaxf(mx, attn[hh][d]);
        float s = 0.f;
        #pragma unroll
        for (int d = 0; d < DEG; ++d) { attn[hh][d] = __expf(attn[hh][d] - mx); s += attn[hh][d]; }
        const float inv = 1.0f / s;
        #pragma unroll
        for (int d = 0; d < DEG; ++d) attn[hh][d] *= inv;
    }

    #pragma unroll
    for (int hh = 0; hh < 3; ++hh) {
        const int h   = wave * 3 + hh;
        const int col = h * HD + lane;
        float o = 0.f;
        #pragma unroll
        for (int d = 0; d < DEG; ++d) {
            const int src = s_src[d];
            const int rel = s_rel[d];
            o += attn[hh][d] * (V[(size_t)(b * NN + src) * HH + col]
                              + Ev[(size_t)rel * HH + col]);
        }
        out[(size_t)seg * HH + col] = o;
    }
}

// ---------------------------------------------------------------------------
extern "C" void kernel_launch(void* const* d_in, const int* in_sizes, int n_in,
                              void* d_out, int out_size, void* d_ws, size_t ws_size,
                              hipStream_t stream)
{
    const float* X  = (const float*)d_in[0];
    const int* eidx = (const int*)d_in[1];
    const float* Wq = (const float*)d_in[2];
    const float* bq = (const float*)d_in[3];
    const float* Wk = (const float*)d_in[4];
    const float* bk = (const float*)d_in[5];
    const float* Wv = (const float*)d_in[6];
    const float* bv = (const float*)d_in[7];
    const float* Ek = (const float*)d_in[8];
    const float* Ev = (const float*)d_in[9];
    float* out = (float*)d_out;

    // workspace layout (16B-aligned slices)
    char* ws = (char*)d_ws;
    float* Q = (float*)ws;                                   // 25165824 B
    float* K = (float*)(ws + 25165824);                      // 25165824 B
    float* V = (float*)(ws + 50331648);                      // 25165824 B
    unsigned short* Xb = (unsigned short*)(ws + 75497472);   // 12582912 B
    unsigned short* Wb = (unsigned short*)(ws + 88080384);   //  3538944 B
    float* biasb = (float*)(ws + 91619328);                  //     9216 B

    convert_x<<<3072, 256, 0, stream>>>(X, Xb);
    convert_w<<<864, 256, 0, stream>>>(Wq, Wk, Wv, bq, bk, bv, Wb, biasb);

    dim3 g(NOUT / 128, MTOT / 128);      // 18 x 64
    qkv_mfma<<<g, 256, 0, stream>>>(Xb, Wb, biasb, Q, K, V);

    attn_kernel<<<MTOT, 256, 0, stream>>>(Q, K, V, Ek, Ev, eidx, out);
}

// Round 3
// 145.024 us; speedup vs baseline: 4.6738x; 1.2988x over previous
//
#include <hip/hip_runtime.h>
#include <hip/hip_bf16.h>

#define BSZ 4
#define NN 2048
#define HH 768
#define NOUT 2304            // 3*HH (Q,K,V fused along N)
#define NHEAD 12
#define HD 64
#define DEG 16
#define MTOT (BSZ * NN)      // 8192
#define ETOT (MTOT * DEG)    // 131072

typedef __attribute__((ext_vector_type(4))) float f32x4;
typedef __attribute__((ext_vector_type(8))) short bf16x8;

__device__ __forceinline__ unsigned short f2bf(float f) {
    union { float f; unsigned int u; } v; v.f = f;
    unsigned int r = v.u + 0x7FFFu + ((v.u >> 16) & 1u);   // RNE
    return (unsigned short)(r >> 16);
}
__device__ __forceinline__ float bf2f(unsigned short u) {
    union { unsigned int u; float f; } v; v.u = ((unsigned int)u) << 16;
    return v.f;
}

__device__ __forceinline__ void gload16(const unsigned short* g, unsigned short* l) {
    __builtin_amdgcn_global_load_lds(
        (const __attribute__((address_space(1))) unsigned int*)g,
        (__attribute__((address_space(3))) unsigned int*)l,
        16, 0, 0);
}

// ---------------------------------------------------------------------------
// X (8192x768 f32) -> bf16.
// ---------------------------------------------------------------------------
__global__ __launch_bounds__(256) void convert_x(
    const float* __restrict__ X, unsigned short* __restrict__ Xb)
{
    const size_t i = ((size_t)blockIdx.x * 256 + threadIdx.x) * 8;
    const float4 a = *(const float4*)(X + i);
    const float4 b = *(const float4*)(X + i + 4);
    bf16x8 o;
    o[0] = f2bf(a.x); o[1] = f2bf(a.y); o[2] = f2bf(a.z); o[3] = f2bf(a.w);
    o[4] = f2bf(b.x); o[5] = f2bf(b.y); o[6] = f2bf(b.z); o[7] = f2bf(b.w);
    *(bf16x8*)(Xb + i) = o;
}

// ---------------------------------------------------------------------------
// Wq/Wk/Wv -> Wcat bf16 [2304][768]; biases -> bias_cat f32.
// ---------------------------------------------------------------------------
__global__ __launch_bounds__(256) void convert_w(
    const float* __restrict__ Wq, const float* __restrict__ Wk,
    const float* __restrict__ Wv,
    const float* __restrict__ bq, const float* __restrict__ bk,
    const float* __restrict__ bv,
    unsigned short* __restrict__ Wb, float* __restrict__ biasb)
{
    const int tid = blockIdx.x * 256 + threadIdx.x;
    const size_t i = (size_t)tid * 8;
    const int row = (int)(i / HH);
    const size_t off = i - (size_t)row * HH;
    const float* src = (row < HH) ? (Wq + (size_t)row * HH)
                     : (row < 2 * HH) ? (Wk + (size_t)(row - HH) * HH)
                                      : (Wv + (size_t)(row - 2 * HH) * HH);
    const float4 a = *(const float4*)(src + off);
    const float4 b = *(const float4*)(src + off + 4);
    bf16x8 o;
    o[0] = f2bf(a.x); o[1] = f2bf(a.y); o[2] = f2bf(a.z); o[3] = f2bf(a.w);
    o[4] = f2bf(b.x); o[5] = f2bf(b.y); o[6] = f2bf(b.z); o[7] = f2bf(b.w);
    *(bf16x8*)(Wb + i) = o;

    if (tid < NOUT) {
        biasb[tid] = (tid < HH) ? bq[tid]
                   : (tid < 2 * HH) ? bk[tid - HH] : bv[tid - 2 * HH];
    }
}

// ---------------------------------------------------------------------------
// Fused QKV GEMM (m97 structure). Q written f32; K,V written bf16 (halves the
// attention kernel's gather traffic).
// ---------------------------------------------------------------------------
__global__ __launch_bounds__(256) void qkv_mfma(
    const unsigned short* __restrict__ Xb,   // [8192][768] bf16
    const unsigned short* __restrict__ Wb,   // [2304][768] bf16
    const float* __restrict__ biasb,         // [2304] f32
    float* __restrict__ Qo,
    unsigned short* __restrict__ Kb, unsigned short* __restrict__ Vb)
{
    __shared__ unsigned short As[128 * 32];
    __shared__ unsigned short Bs[128 * 32];

    const int t    = threadIdx.x;
    const int lane = t & 63;
    const int w    = t >> 6;
    const int wr   = w >> 1;
    const int wc   = w & 1;
    const int bm   = blockIdx.y * 128;
    const int bn   = blockIdx.x * 128;

    const int srow = w * 16 + (lane >> 2);
    const int schk = (lane & 3) * 8;

    const unsigned short* Asrc0 = Xb + (size_t)(bm + srow) * HH + schk;
    const unsigned short* Asrc1 = Asrc0 + (size_t)64 * HH;
    const unsigned short* Bsrc0 = Wb + (size_t)(bn + srow) * HH + schk;
    const unsigned short* Bsrc1 = Bsrc0 + (size_t)64 * HH;

    unsigned short* Adst0 = As + (w * 16) * 32;
    unsigned short* Adst1 = As + (64 + w * 16) * 32;
    unsigned short* Bdst0 = Bs + (w * 16) * 32;
    unsigned short* Bdst1 = Bs + (64 + w * 16) * 32;

    f32x4 acc[4][4];
    #pragma unroll
    for (int mi = 0; mi < 4; ++mi)
        #pragma unroll
        for (int ni = 0; ni < 4; ++ni)
            acc[mi][ni] = (f32x4){0.f, 0.f, 0.f, 0.f};

    const int fr = lane & 15;
    const int fk = (lane >> 4) * 8;

    for (int k0 = 0; k0 < HH; k0 += 32) {
        __syncthreads();
        gload16(Asrc0 + k0, Adst0);
        gload16(Asrc1 + k0, Adst1);
        gload16(Bsrc0 + k0, Bdst0);
        gload16(Bsrc1 + k0, Bdst1);
        __syncthreads();

        bf16x8 a[4], b[4];
        #pragma unroll
        for (int mi = 0; mi < 4; ++mi)
            a[mi] = *(const bf16x8*)(As + (wr * 64 + mi * 16 + fr) * 32 + fk);
        #pragma unroll
        for (int ni = 0; ni < 4; ++ni)
            b[ni] = *(const bf16x8*)(Bs + (wc * 64 + ni * 16 + fr) * 32 + fk);
        #pragma unroll
        for (int mi = 0; mi < 4; ++mi)
            #pragma unroll
            for (int ni = 0; ni < 4; ++ni)
                acc[mi][ni] = __builtin_amdgcn_mfma_f32_16x16x32_bf16(
                    a[mi], b[ni], acc[mi][ni], 0, 0, 0);
    }

    const int crow = (lane >> 4) * 4;    // C/D: row=(lane>>4)*4+reg
    const int ccol = lane & 15;          //      col=lane&15

    if (bn < HH) {
        // Q: f32 store
        #pragma unroll
        for (int ni = 0; ni < 4; ++ni) {
            const int gcol = wc * 64 + ni * 16 + ccol;
            const float bias = biasb[bn + gcol];
            #pragma unroll
            for (int mi = 0; mi < 4; ++mi)
                #pragma unroll
                for (int r = 0; r < 4; ++r) {
                    const int grow = bm + wr * 64 + mi * 16 + crow + r;
                    Qo[(size_t)grow * HH + bn + gcol] = acc[mi][ni][r] + bias;
                }
        }
    } else {
        unsigned short* outb = (bn < 2 * HH) ? Kb : Vb;
        const int ncol0 = (bn < 2 * HH) ? bn - HH : bn - 2 * HH;
        #pragma unroll
        for (int ni = 0; ni < 4; ++ni) {
            const int gcol = wc * 64 + ni * 16 + ccol;
            const float bias = biasb[bn + gcol];
            #pragma unroll
            for (int mi = 0; mi < 4; ++mi)
                #pragma unroll
                for (int r = 0; r < 4; ++r) {
                    const int grow = bm + wr * 64 + mi * 16 + crow + r;
                    outb[(size_t)grow * HH + ncol0 + gcol] = f2bf(acc[mi][ni][r] + bias);
                }
        }
    }
}

// ---------------------------------------------------------------------------
// Edge attention v2. One block per (b,dst) segment.
// Phase A (per wave, 3 heads): lane=(d=lane>>2, c=lane&3); each lane does a
// 16-elem slice of Q.(K+Ek); 2-shfl reduce within the 4-lane group; softmax
// across the 16 edge-groups via 4-step butterfly; attn weights -> LDS.
// Phase B: 192 threads = (head, float4-col); 16-step weighted sum of
// bf16 V + f32 Ev; coalesced float4 store.
// ---------------------------------------------------------------------------
__global__ __launch_bounds__(256) void attn_kernel(
    const float* __restrict__ Q, const unsigned short* __restrict__ Kb,
    const unsigned short* __restrict__ Vb,
    const float* __restrict__ Ek, const float* __restrict__ Ev,
    const int* __restrict__ eidx, float* __restrict__ out)
{
    const int seg  = blockIdx.x;          // b*N + dst
    const int t    = threadIdx.x;
    const int lane = t & 63;
    const int wave = t >> 6;

    __shared__ int s_src[DEG];
    __shared__ int s_rel[DEG];
    __shared__ float s_attn[NHEAD][DEG];
    if (t < DEG) {
        s_src[t] = eidx[2 * ETOT + seg * DEG + t];
        s_rel[t] = eidx[3 * ETOT + seg * DEG + t];
    }
    __syncthreads();

    const int b = seg >> 11;              // seg / N
    const int d = lane >> 2;              // edge group 0..15
    const int c = lane & 3;               // 16-col chunk 0..3

    const size_t krow = (size_t)(b * NN + s_src[d]) * HH;
    const size_t erow = (size_t)s_rel[d] * HH;
    const float* qrow = Q + (size_t)seg * HH;

    #pragma unroll
    for (int hh = 0; hh < 3; ++hh) {
        const int h    = wave * 3 + hh;
        const int col0 = h * HD + c * 16;

        const float4 q0 = *(const float4*)(qrow + col0);
        const float4 q1 = *(const float4*)(qrow + col0 + 4);
        const float4 q2 = *(const float4*)(qrow + col0 + 8);
        const float4 q3 = *(const float4*)(qrow + col0 + 12);
        const bf16x8 k0 = *(const bf16x8*)(Kb + krow + col0);
        const bf16x8 k1 = *(const bf16x8*)(Kb + krow + col0 + 8);
        const float4 e0 = *(const float4*)(Ek + erow + col0);
        const float4 e1 = *(const float4*)(Ek + erow + col0 + 4);
        const float4 e2 = *(const float4*)(Ek + erow + col0 + 8);
        const float4 e3 = *(const float4*)(Ek + erow + col0 + 12);

        float p = 0.f;
        p += q0.x * (bf2f((unsigned short)k0[0]) + e0.x);
        p += q0.y * (bf2f((unsigned short)k0[1]) + e0.y);
        p += q0.z * (bf2f((unsigned short)k0[2]) + e0.z);
        p += q0.w * (bf2f((unsigned short)k0[3]) + e0.w);
        p += q1.x * (bf2f((unsigned short)k0[4]) + e1.x);
        p += q1.y * (bf2f((unsigned short)k0[5]) + e1.y);
        p += q1.z * (bf2f((unsigned short)k0[6]) + e1.z);
        p += q1.w * (bf2f((unsigned short)k0[7]) + e1.w);
        p += q2.x * (bf2f((unsigned short)k1[0]) + e2.x);
        p += q2.y * (bf2f((unsigned short)k1[1]) + e2.y);
        p += q2.z * (bf2f((unsigned short)k1[2]) + e2.z);
        p += q2.w * (bf2f((unsigned short)k1[3]) + e2.w);
        p += q3.x * (bf2f((unsigned short)k1[4]) + e3.x);
        p += q3.y * (bf2f((unsigned short)k1[5]) + e3.y);
        p += q3.z * (bf2f((unsigned short)k1[6]) + e3.z);
        p += q3.w * (bf2f((unsigned short)k1[7]) + e3.w);

        // reduce the 4 chunk-lanes -> full dot in each lane of the group
        p += __shfl_xor(p, 1, 64);
        p += __shfl_xor(p, 2, 64);
        const float logit = p * 0.125f;

        // softmax across the 16 edge-groups (butterfly over bits 2..5)
        float mx = logit;
        #pragma unroll
        for (int m = 4; m < 64; m <<= 1) mx = fmaxf(mx, __shfl_xor(mx, m, 64));
        const float ex = __expf(logit - mx);
        float s = ex;
        #pragma unroll
        for (int m = 4; m < 64; m <<= 1) s += __shfl_xor(s, m, 64);
        if (c == 0) s_attn[h][d] = ex / s;
    }
    __syncthreads();

    if (t < NHEAD * 16) {
        const int h    = t >> 4;
        const int cc   = t & 15;
        const int col0 = h * HD + cc * 4;
        f32x4 acc = (f32x4){0.f, 0.f, 0.f, 0.f};
        #pragma unroll
        for (int d2 = 0; d2 < DEG; ++d2) {
            const float aw = s_attn[h][d2];
            const unsigned short* vp = Vb + (size_t)(b * NN + s_src[d2]) * HH + col0;
            const float* ep = Ev + (size_t)s_rel[d2] * HH + col0;
            const ushort4 v4 = *(const ushort4*)vp;
            const float4 ev = *(const float4*)ep;
            acc[0] += aw * (bf2f(v4.x) + ev.x);
            acc[1] += aw * (bf2f(v4.y) + ev.y);
            acc[2] += aw * (bf2f(v4.z) + ev.z);
            acc[3] += aw * (bf2f(v4.w) + ev.w);
        }
        *(f32x4*)(out + (size_t)seg * HH + col0) = acc;
    }
}

// ---------------------------------------------------------------------------
extern "C" void kernel_launch(void* const* d_in, const int* in_sizes, int n_in,
                              void* d_out, int out_size, void* d_ws, size_t ws_size,
                              hipStream_t stream)
{
    const float* X  = (const float*)d_in[0];
    const int* eidx = (const int*)d_in[1];
    const float* Wq = (const float*)d_in[2];
    const float* bq = (const float*)d_in[3];
    const float* Wk = (const float*)d_in[4];
    const float* bk = (const float*)d_in[5];
    const float* Wv = (const float*)d_in[6];
    const float* bv = (const float*)d_in[7];
    const float* Ek = (const float*)d_in[8];
    const float* Ev = (const float*)d_in[9];
    float* out = (float*)d_out;

    // workspace layout (16B-aligned slices)
    char* ws = (char*)d_ws;
    float* Q           = (float*)ws;                          // 25165824 B
    unsigned short* Kb = (unsigned short*)(ws + 25165824);    // 12582912 B
    unsigned short* Vb = (unsigned short*)(ws + 37748736);    // 12582912 B
    unsigned short* Xb = (unsigned short*)(ws + 50331648);    // 12582912 B
    unsigned short* Wb = (unsigned short*)(ws + 62914560);    //  3538944 B
    float* biasb       = (float*)(ws + 66453504);             //     9216 B

    convert_x<<<3072, 256, 0, stream>>>(X, Xb);
    convert_w<<<864, 256, 0, stream>>>(Wq, Wk, Wv, bq, bk, bv, Wb, biasb);

    dim3 g(NOUT / 128, MTOT / 128);      // 18 x 64
    qkv_mfma<<<g, 256, 0, stream>>>(Xb, Wb, biasb, Q, Kb, Vb);

    attn_kernel<<<MTOT, 256, 0, stream>>>(Q, Kb, Vb, Ek, Ev, eidx, out);
}

// Round 4
// 127.560 us; speedup vs baseline: 5.3136x; 1.1369x over previous
//
#include <hip/hip_runtime.h>
#include <hip/hip_bf16.h>

#define BSZ 4
#define NN 2048
#define HH 768
#define NOUT 3072            // 3*HH (Q,K,V) + 768 (S2 = Q·Ek^T per head/rel)
#define NHEAD 12
#define HD 64
#define DEG 16
#define NREL 64
#define MTOT (BSZ * NN)      // 8192
#define ETOT (MTOT * DEG)    // 131072

typedef __attribute__((ext_vector_type(4))) float f32x4;
typedef __attribute__((ext_vector_type(8))) short bf16x8;

__device__ __forceinline__ unsigned short f2bf(float f) {
    union { float f; unsigned int u; } v; v.f = f;
    unsigned int r = v.u + 0x7FFFu + ((v.u >> 16) & 1u);   // RNE
    return (unsigned short)(r >> 16);
}
__device__ __forceinline__ float bf2f(unsigned short u) {
    union { unsigned int u; float f; } v; v.u = ((unsigned int)u) << 16;
    return v.f;
}

__device__ __forceinline__ void gload16(const unsigned short* g, unsigned short* l) {
    __builtin_amdgcn_global_load_lds(
        (const __attribute__((address_space(1))) unsigned int*)g,
        (__attribute__((address_space(3))) unsigned int*)l,
        16, 0, 0);
}

// ---------------------------------------------------------------------------
// X (8192x768 f32) -> bf16.
// ---------------------------------------------------------------------------
__global__ __launch_bounds__(256) void convert_x(
    const float* __restrict__ X, unsigned short* __restrict__ Xb)
{
    const size_t i = ((size_t)blockIdx.x * 256 + threadIdx.x) * 8;
    const float4 a = *(const float4*)(X + i);
    const float4 b = *(const float4*)(X + i + 4);
    bf16x8 o;
    o[0] = f2bf(a.x); o[1] = f2bf(a.y); o[2] = f2bf(a.z); o[3] = f2bf(a.w);
    o[4] = f2bf(b.x); o[5] = f2bf(b.y); o[6] = f2bf(b.z); o[7] = f2bf(b.w);
    *(bf16x8*)(Xb + i) = o;
}

// ---------------------------------------------------------------------------
// Wq/Wk/Wv -> Wcat bf16 rows [0,2304); biases -> biasb[0,2304).
// ---------------------------------------------------------------------------
__global__ __launch_bounds__(256) void convert_w(
    const float* __restrict__ Wq, const float* __restrict__ Wk,
    const float* __restrict__ Wv,
    const float* __restrict__ bq, const float* __restrict__ bk,
    const float* __restrict__ bv,
    unsigned short* __restrict__ Wb, float* __restrict__ biasb)
{
    const int tid = blockIdx.x * 256 + threadIdx.x;
    const size_t i = (size_t)tid * 8;
    const int row = (int)(i / HH);
    const size_t off = i - (size_t)row * HH;
    const float* src = (row < HH) ? (Wq + (size_t)row * HH)
                     : (row < 2 * HH) ? (Wk + (size_t)(row - HH) * HH)
                                      : (Wv + (size_t)(row - 2 * HH) * HH);
    const float4 a = *(const float4*)(src + off);
    const float4 b = *(const float4*)(src + off + 4);
    bf16x8 o;
    o[0] = f2bf(a.x); o[1] = f2bf(a.y); o[2] = f2bf(a.z); o[3] = f2bf(a.w);
    o[4] = f2bf(b.x); o[5] = f2bf(b.y); o[6] = f2bf(b.z); o[7] = f2bf(b.w);
    *(bf16x8*)(Wb + i) = o;

    if (tid < 3 * HH) {
        biasb[tid] = (tid < HH) ? bq[tid]
                   : (tid < 2 * HH) ? bk[tid - HH] : bv[tid - 2 * HH];
    }
}

// ---------------------------------------------------------------------------
// Ev (64x768 f32) -> bf16.  49152 elems = 24 blocks * 256 * 8.
// ---------------------------------------------------------------------------
__global__ __launch_bounds__(256) void convert_e(
    const float* __restrict__ Ev, unsigned short* __restrict__ Evb)
{
    const size_t i = ((size_t)blockIdx.x * 256 + threadIdx.x) * 8;
    const float4 a = *(const float4*)(Ev + i);
    const float4 b = *(const float4*)(Ev + i + 4);
    bf16x8 o;
    o[0] = f2bf(a.x); o[1] = f2bf(a.y); o[2] = f2bf(a.z); o[3] = f2bf(a.w);
    o[4] = f2bf(b.x); o[5] = f2bf(b.y); o[6] = f2bf(b.z); o[7] = f2bf(b.w);
    *(bf16x8*)(Evb + i) = o;
}

// ---------------------------------------------------------------------------
// W2[h*64+rel, i] = sum_{jj<64} Wq[h*64+jj, i] * Ek[rel, h*64+jj]
// -> Wb rows [2304, 3072) (bf16);  bias2 -> biasb[2304+r2].
// grid (3, 768): x = 256-col chunk of i, y = r2.
// ---------------------------------------------------------------------------
__global__ __launch_bounds__(256) void build_w2(
    const float* __restrict__ Wq, const float* __restrict__ bq,
    const float* __restrict__ Ek,
    unsigned short* __restrict__ Wb, float* __restrict__ biasb)
{
    const int r2 = blockIdx.y;          // h*64 + rel
    const int h = r2 >> 6, rel = r2 & 63;
    const int i = blockIdx.x * 256 + threadIdx.x;
    const int t = threadIdx.x;

    __shared__ float s_e[64];
    if (t < 64) s_e[t] = Ek[(size_t)rel * HH + h * 64 + t];
    __syncthreads();

    float acc = 0.f;
    #pragma unroll 8
    for (int jj = 0; jj < 64; ++jj)
        acc += Wq[(size_t)(h * 64 + jj) * HH + i] * s_e[jj];
    Wb[(size_t)(3 * HH + r2) * HH + i] = f2bf(acc);

    if (blockIdx.x == 0 && t == 0) {
        float b2 = 0.f;
        for (int jj = 0; jj < 64; ++jj) b2 += bq[h * 64 + jj] * s_e[jj];
        biasb[3 * HH + r2] = b2;
    }
}

// ---------------------------------------------------------------------------
// Fused GEMM: C[m,n] = Xb[m,:].Wb[n,:] + biasb[n], m<8192, n<3072.
// n in [0,768)->Qb bf16, [768,1536)->Kb bf16, [1536,2304)->Vb bf16,
// [2304,3072)->S2 f32 (the Q·Ek logit term, head-major: h*64+rel).
// m97 structure: 128x128 tile, BK=32, 4 waves, 4x4 16x16x32 bf16 MFMA.
// ---------------------------------------------------------------------------
__global__ __launch_bounds__(256) void qkv_mfma(
    const unsigned short* __restrict__ Xb,
    const unsigned short* __restrict__ Wb,
    const float* __restrict__ biasb,
    unsigned short* __restrict__ Qb,
    unsigned short* __restrict__ Kb, unsigned short* __restrict__ Vb,
    float* __restrict__ S2)
{
    __shared__ unsigned short As[128 * 32];
    __shared__ unsigned short Bs[128 * 32];

    const int t    = threadIdx.x;
    const int lane = t & 63;
    const int w    = t >> 6;
    const int wr   = w >> 1;
    const int wc   = w & 1;
    const int bm   = blockIdx.y * 128;
    const int bn   = blockIdx.x * 128;

    const int srow = w * 16 + (lane >> 2);
    const int schk = (lane & 3) * 8;

    const unsigned short* Asrc0 = Xb + (size_t)(bm + srow) * HH + schk;
    const unsigned short* Asrc1 = Asrc0 + (size_t)64 * HH;
    const unsigned short* Bsrc0 = Wb + (size_t)(bn + srow) * HH + schk;
    const unsigned short* Bsrc1 = Bsrc0 + (size_t)64 * HH;

    unsigned short* Adst0 = As + (w * 16) * 32;
    unsigned short* Adst1 = As + (64 + w * 16) * 32;
    unsigned short* Bdst0 = Bs + (w * 16) * 32;
    unsigned short* Bdst1 = Bs + (64 + w * 16) * 32;

    f32x4 acc[4][4];
    #pragma unroll
    for (int mi = 0; mi < 4; ++mi)
        #pragma unroll
        for (int ni = 0; ni < 4; ++ni)
            acc[mi][ni] = (f32x4){0.f, 0.f, 0.f, 0.f};

    const int fr = lane & 15;
    const int fk = (lane >> 4) * 8;

    for (int k0 = 0; k0 < HH; k0 += 32) {
        __syncthreads();
        gload16(Asrc0 + k0, Adst0);
        gload16(Asrc1 + k0, Adst1);
        gload16(Bsrc0 + k0, Bdst0);
        gload16(Bsrc1 + k0, Bdst1);
        __syncthreads();

        bf16x8 a[4], b[4];
        #pragma unroll
        for (int mi = 0; mi < 4; ++mi)
            a[mi] = *(const bf16x8*)(As + (wr * 64 + mi * 16 + fr) * 32 + fk);
        #pragma unroll
        for (int ni = 0; ni < 4; ++ni)
            b[ni] = *(const bf16x8*)(Bs + (wc * 64 + ni * 16 + fr) * 32 + fk);
        #pragma unroll
        for (int mi = 0; mi < 4; ++mi)
            #pragma unroll
            for (int ni = 0; ni < 4; ++ni)
                acc[mi][ni] = __builtin_amdgcn_mfma_f32_16x16x32_bf16(
                    a[mi], b[ni], acc[mi][ni], 0, 0, 0);
    }

    const int crow = (lane >> 4) * 4;    // C/D: row=(lane>>4)*4+reg
    const int ccol = lane & 15;          //      col=lane&15

    if (bn < 3 * HH) {
        unsigned short* outb; int ncol0;
        if (bn < HH)          { outb = Qb; ncol0 = bn; }
        else if (bn < 2 * HH) { outb = Kb; ncol0 = bn - HH; }
        else                  { outb = Vb; ncol0 = bn - 2 * HH; }
        #pragma unroll
        for (int ni = 0; ni < 4; ++ni) {
            const int gcol = wc * 64 + ni * 16 + ccol;
            const float bias = biasb[bn + gcol];
            #pragma unroll
            for (int mi = 0; mi < 4; ++mi)
                #pragma unroll
                for (int r = 0; r < 4; ++r) {
                    const int grow = bm + wr * 64 + mi * 16 + crow + r;
                    outb[(size_t)grow * HH + ncol0 + gcol] = f2bf(acc[mi][ni][r] + bias);
                }
        }
    } else {
        const int ncol0 = bn - 3 * HH;
        #pragma unroll
        for (int ni = 0; ni < 4; ++ni) {
            const int gcol = wc * 64 + ni * 16 + ccol;
            const float bias = biasb[bn + gcol];
            #pragma unroll
            for (int mi = 0; mi < 4; ++mi)
                #pragma unroll
                for (int r = 0; r < 4; ++r) {
                    const int grow = bm + wr * 64 + mi * 16 + crow + r;
                    S2[(size_t)grow * HH + ncol0 + gcol] = acc[mi][ni][r] + bias;
                }
        }
    }
}

// ---------------------------------------------------------------------------
// Edge attention v3. One block per (b,dst) segment.
// S2 row (Q·Ek per h,rel) staged in LDS; logits = (Q·K + S2[h,rel])/8.
// Phase A: lane=(d=lane>>2, c=lane&3), 16-elem bf16 dot slices, 2-shfl
// group reduce, 4-step butterfly softmax over the 16 edge groups.
// Phase B: 192 threads (head, 4-col), bf16 V + bf16 Ev weighted sum.
// ---------------------------------------------------------------------------
__global__ __launch_bounds__(256) void attn_kernel(
    const unsigned short* __restrict__ Qb, const unsigned short* __restrict__ Kb,
    const unsigned short* __restrict__ Vb,
    const float* __restrict__ S2, const unsigned short* __restrict__ Evb,
    const int* __restrict__ eidx, float* __restrict__ out)
{
    const int seg  = blockIdx.x;          // b*N + dst
    const int t    = threadIdx.x;
    const int lane = t & 63;
    const int wave = t >> 6;

    __shared__ int s_src[DEG];
    __shared__ int s_rel[DEG];
    __shared__ float s_S2row[HH];
    __shared__ float s_attn[NHEAD][DEG];
    if (t < DEG) {
        s_src[t] = eidx[2 * ETOT + seg * DEG + t];
        s_rel[t] = eidx[3 * ETOT + seg * DEG + t];
    }
    if (t < 192)
        *(f32x4*)(s_S2row + t * 4) = *(const f32x4*)(S2 + (size_t)seg * HH + t * 4);
    __syncthreads();

    const int b = seg >> 11;              // seg / N
    const int d = lane >> 2;              // edge group 0..15
    const int c = lane & 3;               // 16-col chunk 0..3

    const size_t krow = (size_t)(b * NN + s_src[d]) * HH;
    const int rel_d = s_rel[d];
    const size_t qrow = (size_t)seg * HH;

    #pragma unroll
    for (int hh = 0; hh < 3; ++hh) {
        const int h    = wave * 3 + hh;
        const int col0 = h * HD + c * 16;

        const bf16x8 q0 = *(const bf16x8*)(Qb + qrow + col0);
        const bf16x8 q1 = *(const bf16x8*)(Qb + qrow + col0 + 8);
        const bf16x8 k0 = *(const bf16x8*)(Kb + krow + col0);
        const bf16x8 k1 = *(const bf16x8*)(Kb + krow + col0 + 8);

        float p = 0.f;
        #pragma unroll
        for (int i = 0; i < 8; ++i)
            p += bf2f((unsigned short)q0[i]) * bf2f((unsigned short)k0[i]);
        #pragma unroll
        for (int i = 0; i < 8; ++i)
            p += bf2f((unsigned short)q1[i]) * bf2f((unsigned short)k1[i]);

        p += __shfl_xor(p, 1, 64);
        p += __shfl_xor(p, 2, 64);
        const float logit = (p + s_S2row[h * HD + rel_d]) * 0.125f;

        float mx = logit;
        #pragma unroll
        for (int m = 4; m < 64; m <<= 1) mx = fmaxf(mx, __shfl_xor(mx, m, 64));
        const float ex = __expf(logit - mx);
        float s = ex;
        #pragma unroll
        for (int m = 4; m < 64; m <<= 1) s += __shfl_xor(s, m, 64);
        if (c == 0) s_attn[h][d] = ex / s;
    }
    __syncthreads();

    if (t < NHEAD * 16) {
        const int h    = t >> 4;
        const int cc   = t & 15;
        const int col0 = h * HD + cc * 4;
        f32x4 acc = (f32x4){0.f, 0.f, 0.f, 0.f};
        #pragma unroll
        for (int d2 = 0; d2 < DEG; ++d2) {
            const float aw = s_attn[h][d2];
            const ushort4 v4 = *(const ushort4*)(Vb + (size_t)(b * NN + s_src[d2]) * HH + col0);
            const ushort4 e4 = *(const ushort4*)(Evb + (size_t)s_rel[d2] * HH + col0);
            acc[0] += aw * (bf2f(v4.x) + bf2f(e4.x));
            acc[1] += aw * (bf2f(v4.y) + bf2f(e4.y));
            acc[2] += aw * (bf2f(v4.z) + bf2f(e4.z));
            acc[3] += aw * (bf2f(v4.w) + bf2f(e4.w));
        }
        *(f32x4*)(out + (size_t)seg * HH + col0) = acc;
    }
}

// ---------------------------------------------------------------------------
extern "C" void kernel_launch(void* const* d_in, const int* in_sizes, int n_in,
                              void* d_out, int out_size, void* d_ws, size_t ws_size,
                              hipStream_t stream)
{
    const float* X  = (const float*)d_in[0];
    const int* eidx = (const int*)d_in[1];
    const float* Wq = (const float*)d_in[2];
    const float* bq = (const float*)d_in[3];
    const float* Wk = (const float*)d_in[4];
    const float* bk = (const float*)d_in[5];
    const float* Wv = (const float*)d_in[6];
    const float* bv = (const float*)d_in[7];
    const float* Ek = (const float*)d_in[8];
    const float* Ev = (const float*)d_in[9];
    float* out = (float*)d_out;

    // workspace layout (16B-aligned slices), total ~80.3 MB
    char* ws = (char*)d_ws;
    unsigned short* Qb = (unsigned short*)ws;                 // 12582912 B
    unsigned short* Kb = (unsigned short*)(ws + 12582912);    // 12582912 B
    unsigned short* Vb = (unsigned short*)(ws + 25165824);    // 12582912 B
    unsigned short* Xb = (unsigned short*)(ws + 37748736);    // 12582912 B
    unsigned short* Wb = (unsigned short*)(ws + 50331648);    //  4718592 B (3072x768)
    float* biasb       = (float*)(ws + 55050240);             //    12288 B
    float* S2          = (float*)(ws + 55062528);             // 25165824 B
    unsigned short* Evb= (unsigned short*)(ws + 80228352);    //    98304 B

    convert_x<<<3072, 256, 0, stream>>>(X, Xb);
    convert_w<<<864, 256, 0, stream>>>(Wq, Wk, Wv, bq, bk, bv, Wb, biasb);
    convert_e<<<24, 256, 0, stream>>>(Ev, Evb);
    build_w2<<<dim3(3, 768), 256, 0, stream>>>(Wq, bq, Ek, Wb, biasb);

    dim3 g(NOUT / 128, MTOT / 128);      // 24 x 64
    qkv_mfma<<<g, 256, 0, stream>>>(Xb, Wb, biasb, Qb, Kb, Vb, S2);

    attn_kernel<<<MTOT, 256, 0, stream>>>(Qb, Kb, Vb, S2, Evb, eidx, out);
}

// Round 5
// 115.597 us; speedup vs baseline: 5.8636x; 1.1035x over previous
//
#include <hip/hip_runtime.h>
#include <hip/hip_bf16.h>

#define BSZ 4
#define NN 2048
#define HH 768
#define NOUT 2304            // 3*HH (Q,K,V fused along N)
#define NHEAD 12
#define HD 64
#define DEG 16
#define NREL 64
#define MTOT (BSZ * NN)      // 8192
#define ETOT (MTOT * DEG)    // 131072

typedef __attribute__((ext_vector_type(4))) float f32x4;
typedef __attribute__((ext_vector_type(8))) short bf16x8;

__device__ __forceinline__ unsigned short f2bf(float f) {
    union { float f; unsigned int u; } v; v.f = f;
    unsigned int r = v.u + 0x7FFFu + ((v.u >> 16) & 1u);   // RNE
    return (unsigned short)(r >> 16);
}
__device__ __forceinline__ float bf2f(unsigned short u) {
    union { unsigned int u; float f; } v; v.u = ((unsigned int)u) << 16;
    return v.f;
}

__device__ __forceinline__ void gload16(const unsigned short* g, unsigned short* l) {
    __builtin_amdgcn_global_load_lds(
        (const __attribute__((address_space(1))) unsigned int*)g,
        (__attribute__((address_space(3))) unsigned int*)l,
        16, 0, 0);
}

// ---------------------------------------------------------------------------
// X (8192x768 f32) -> bf16.
// ---------------------------------------------------------------------------
__global__ __launch_bounds__(256) void convert_x(
    const float* __restrict__ X, unsigned short* __restrict__ Xb)
{
    const size_t i = ((size_t)blockIdx.x * 256 + threadIdx.x) * 8;
    const float4 a = *(const float4*)(X + i);
    const float4 b = *(const float4*)(X + i + 4);
    bf16x8 o;
    o[0] = f2bf(a.x); o[1] = f2bf(a.y); o[2] = f2bf(a.z); o[3] = f2bf(a.w);
    o[4] = f2bf(b.x); o[5] = f2bf(b.y); o[6] = f2bf(b.z); o[7] = f2bf(b.w);
    *(bf16x8*)(Xb + i) = o;
}

// ---------------------------------------------------------------------------
// Wq/Wk/Wv -> Wcat bf16 rows [0,2304); biases -> biasb[0,2304).
// ---------------------------------------------------------------------------
__global__ __launch_bounds__(256) void convert_w(
    const float* __restrict__ Wq, const float* __restrict__ Wk,
    const float* __restrict__ Wv,
    const float* __restrict__ bq, const float* __restrict__ bk,
    const float* __restrict__ bv,
    unsigned short* __restrict__ Wb, float* __restrict__ biasb)
{
    const int tid = blockIdx.x * 256 + threadIdx.x;
    const size_t i = (size_t)tid * 8;
    const int row = (int)(i / HH);
    const size_t off = i - (size_t)row * HH;
    const float* src = (row < HH) ? (Wq + (size_t)row * HH)
                     : (row < 2 * HH) ? (Wk + (size_t)(row - HH) * HH)
                                      : (Wv + (size_t)(row - 2 * HH) * HH);
    const float4 a = *(const float4*)(src + off);
    const float4 b = *(const float4*)(src + off + 4);
    bf16x8 o;
    o[0] = f2bf(a.x); o[1] = f2bf(a.y); o[2] = f2bf(a.z); o[3] = f2bf(a.w);
    o[4] = f2bf(b.x); o[5] = f2bf(b.y); o[6] = f2bf(b.z); o[7] = f2bf(b.w);
    *(bf16x8*)(Wb + i) = o;

    if (tid < NOUT) {
        biasb[tid] = (tid < HH) ? bq[tid]
                   : (tid < 2 * HH) ? bk[tid - HH] : bv[tid - 2 * HH];
    }
}

// ---------------------------------------------------------------------------
// Ek, Ev (each 64x768 f32) -> bf16. 2*49152 elems = 48 blocks * 256 * 8.
// ---------------------------------------------------------------------------
__global__ __launch_bounds__(256) void convert_e(
    const float* __restrict__ Ek, const float* __restrict__ Ev,
    unsigned short* __restrict__ Ekb, unsigned short* __restrict__ Evb)
{
    const int half = blockIdx.x >> 4;               // 0: Ek, 1: Ev  (24 blocks each)
    const int bx   = blockIdx.x & 15;
    const float* src = half ? Ev : Ek;
    unsigned short* dst = half ? Evb : Ekb;
    // 24 blocks needed; grid.x = 48 with 16-block halves would misalign, so:
    // use 2*24 grid, decode explicitly below instead.
    (void)bx;
    const int blk = (int)blockIdx.x;
    const int h2  = blk / 24;                        // 0 or 1
    const int b2  = blk % 24;
    src = h2 ? Ev : Ek;
    dst = h2 ? Evb : Ekb;
    const size_t i = ((size_t)b2 * 256 + threadIdx.x) * 8;
    const float4 a = *(const float4*)(src + i);
    const float4 b = *(const float4*)(src + i + 4);
    bf16x8 o;
    o[0] = f2bf(a.x); o[1] = f2bf(a.y); o[2] = f2bf(a.z); o[3] = f2bf(a.w);
    o[4] = f2bf(b.x); o[5] = f2bf(b.y); o[6] = f2bf(b.z); o[7] = f2bf(b.w);
    *(bf16x8*)(dst + i) = o;
}

// ---------------------------------------------------------------------------
// Fused QKV GEMM: C[m,n] = Xb[m,:].Wb[n,:] + biasb[n], m<8192, n<2304.
// m97 structure: 128x128 tile, BK=32, 4 waves, 4x4 16x16x32 bf16 MFMA.
// Operand-SWAPPED mfma (b,a) so D's reg-indexed dim = N -> each lane holds 4
// consecutive output columns -> packed ushort4 stores (16 stores/thread).
// Bijective XCD swizzle (1152 wg = 8 x 144).
// ---------------------------------------------------------------------------
__global__ __launch_bounds__(256) void qkv_mfma(
    const unsigned short* __restrict__ Xb,
    const unsigned short* __restrict__ Wb,
    const float* __restrict__ biasb,
    unsigned short* __restrict__ Qb,
    unsigned short* __restrict__ Kb, unsigned short* __restrict__ Vb)
{
    __shared__ unsigned short As[128 * 32];
    __shared__ unsigned short Bs[128 * 32];

    // XCD-aware swizzle: nwg = 18*64 = 1152, 144 per XCD
    const int bid  = blockIdx.y * 18 + blockIdx.x;
    const int swz  = (bid & 7) * 144 + (bid >> 3);
    const int bxn  = swz % 18;
    const int byn  = swz / 18;

    const int t    = threadIdx.x;
    const int lane = t & 63;
    const int w    = t >> 6;
    const int wr   = w >> 1;
    const int wc   = w & 1;
    const int bm   = byn * 128;
    const int bn   = bxn * 128;

    const int srow = w * 16 + (lane >> 2);
    const int schk = (lane & 3) * 8;

    const unsigned short* Asrc0 = Xb + (size_t)(bm + srow) * HH + schk;
    const unsigned short* Asrc1 = Asrc0 + (size_t)64 * HH;
    const unsigned short* Bsrc0 = Wb + (size_t)(bn + srow) * HH + schk;
    const unsigned short* Bsrc1 = Bsrc0 + (size_t)64 * HH;

    unsigned short* Adst0 = As + (w * 16) * 32;
    unsigned short* Adst1 = As + (64 + w * 16) * 32;
    unsigned short* Bdst0 = Bs + (w * 16) * 32;
    unsigned short* Bdst1 = Bs + (64 + w * 16) * 32;

    f32x4 acc[4][4];     // [ni][mi] after operand swap
    #pragma unroll
    for (int ni = 0; ni < 4; ++ni)
        #pragma unroll
        for (int mi = 0; mi < 4; ++mi)
            acc[ni][mi] = (f32x4){0.f, 0.f, 0.f, 0.f};

    const int fr = lane & 15;
    const int fk = (lane >> 4) * 8;

    for (int k0 = 0; k0 < HH; k0 += 32) {
        __syncthreads();
        gload16(Asrc0 + k0, Adst0);
        gload16(Asrc1 + k0, Adst1);
        gload16(Bsrc0 + k0, Bdst0);
        gload16(Bsrc1 + k0, Bdst1);
        __syncthreads();

        bf16x8 a[4], b[4];
        #pragma unroll
        for (int mi = 0; mi < 4; ++mi)
            a[mi] = *(const bf16x8*)(As + (wr * 64 + mi * 16 + fr) * 32 + fk);
        #pragma unroll
        for (int ni = 0; ni < 4; ++ni)
            b[ni] = *(const bf16x8*)(Bs + (wc * 64 + ni * 16 + fr) * 32 + fk);
        #pragma unroll
        for (int ni = 0; ni < 4; ++ni)
            #pragma unroll
            for (int mi = 0; mi < 4; ++mi)
                acc[ni][mi] = __builtin_amdgcn_mfma_f32_16x16x32_bf16(
                    b[ni], a[mi], acc[ni][mi], 0, 0, 0);
    }

    // epilogue: D row-dim (reg-indexed) = N, col-dim (lane&15) = M
    const int cm = lane & 15;            // m-local within 16
    const int cn = (lane >> 4) * 4;      // n-local base within 16

    unsigned short* outb; int ncol0;
    if (bn < HH)          { outb = Qb; ncol0 = bn; }
    else if (bn < 2 * HH) { outb = Kb; ncol0 = bn - HH; }
    else                  { outb = Vb; ncol0 = bn - 2 * HH; }

    #pragma unroll
    for (int ni = 0; ni < 4; ++ni) {
        const int nloc = wc * 64 + ni * 16 + cn;           // within 128-tile
        const float4 b4 = *(const float4*)(biasb + bn + nloc);
        #pragma unroll
        for (int mi = 0; mi < 4; ++mi) {
            const int grow = bm + wr * 64 + mi * 16 + cm;
            ushort4 o;
            o.x = f2bf(acc[ni][mi][0] + b4.x);
            o.y = f2bf(acc[ni][mi][1] + b4.y);
            o.z = f2bf(acc[ni][mi][2] + b4.z);
            o.w = f2bf(acc[ni][mi][3] + b4.w);
            *(ushort4*)(outb + (size_t)grow * HH + ncol0 + nloc) = o;
        }
    }
}

// ---------------------------------------------------------------------------
// S2[m, h*64+rel] = Qb[m, hslice] . Ekb[rel, hslice]   (K = 64, bf16 MFMA).
// Qb already contains bq, so no bias. Output bf16.
// grid (128, 12): x = 64-row m-tile, y = head. 4 waves: wave w -> rows
// m0 = bx*64 + w*16. Operand-swapped mfma -> packed ushort4 stores.
// ---------------------------------------------------------------------------
__global__ __launch_bounds__(256) void s2_kernel(
    const unsigned short* __restrict__ Qb,
    const unsigned short* __restrict__ Ekb,
    unsigned short* __restrict__ S2b)
{
    const int t    = threadIdx.x;
    const int lane = t & 63;
    const int w    = t >> 6;
    const int h    = blockIdx.y;
    const int m0   = blockIdx.x * 64 + w * 16;

    const int fr  = lane & 15;
    const int fk8 = (lane >> 4) * 8;

    // A frags: Q rows (m), B frags: Ek rows (rel)
    bf16x8 a[2];
    #pragma unroll
    for (int kk = 0; kk < 2; ++kk)
        a[kk] = *(const bf16x8*)(Qb + (size_t)(m0 + fr) * HH + h * HD + kk * 32 + fk8);

    #pragma unroll
    for (int rt = 0; rt < 4; ++rt) {
        f32x4 acc = (f32x4){0.f, 0.f, 0.f, 0.f};
        #pragma unroll
        for (int kk = 0; kk < 2; ++kk) {
            const bf16x8 bfr = *(const bf16x8*)(
                Ekb + (size_t)(rt * 16 + fr) * HH + h * HD + kk * 32 + fk8);
            acc = __builtin_amdgcn_mfma_f32_16x16x32_bf16(bfr, a[kk], acc, 0, 0, 0);
        }
        // D: reg dim = rel, lane&15 = m
        const int m   = m0 + (lane & 15);
        const int rel = rt * 16 + (lane >> 4) * 4;
        ushort4 o;
        o.x = f2bf(acc[0]); o.y = f2bf(acc[1]);
        o.z = f2bf(acc[2]); o.w = f2bf(acc[3]);
        *(ushort4*)(S2b + (size_t)m * HH + h * HD + rel) = o;
    }
}

// ---------------------------------------------------------------------------
// Edge attention v4. One block per (b,dst) segment.
// S2 row (bf16) staged in LDS; logits = (Q.K + S2[h,rel])/8.
// Phase A: lane=(d=lane>>2, c=lane&3), 16-elem bf16 dot slices, 2-shfl
// group reduce, 4-step butterfly softmax over the 16 edge groups.
// Phase B: 192 threads (head, 4-col), bf16 V + bf16 Ev weighted sum.
// ---------------------------------------------------------------------------
__global__ __launch_bounds__(256) void attn_kernel(
    const unsigned short* __restrict__ Qb, const unsigned short* __restrict__ Kb,
    const unsigned short* __restrict__ Vb,
    const unsigned short* __restrict__ S2b, const unsigned short* __restrict__ Evb,
    const int* __restrict__ eidx, float* __restrict__ out)
{
    const int seg  = blockIdx.x;          // b*N + dst
    const int t    = threadIdx.x;
    const int lane = t & 63;
    const int wave = t >> 6;

    __shared__ int s_src[DEG];
    __shared__ int s_rel[DEG];
    __shared__ unsigned short s_S2row[HH];
    __shared__ float s_attn[NHEAD][DEG];
    if (t < DEG) {
        s_src[t] = eidx[2 * ETOT + seg * DEG + t];
        s_rel[t] = eidx[3 * ETOT + seg * DEG + t];
    }
    if (t < 96)
        *(bf16x8*)(s_S2row + t * 8) = *(const bf16x8*)(S2b + (size_t)seg * HH + t * 8);
    __syncthreads();

    const int b = seg >> 11;              // seg / N
    const int d = lane >> 2;              // edge group 0..15
    const int c = lane & 3;               // 16-col chunk 0..3

    const size_t krow = (size_t)(b * NN + s_src[d]) * HH;
    const int rel_d = s_rel[d];
    const size_t qrow = (size_t)seg * HH;

    #pragma unroll
    for (int hh = 0; hh < 3; ++hh) {
        const int h    = wave * 3 + hh;
        const int col0 = h * HD + c * 16;

        const bf16x8 q0 = *(const bf16x8*)(Qb + qrow + col0);
        const bf16x8 q1 = *(const bf16x8*)(Qb + qrow + col0 + 8);
        const bf16x8 k0 = *(const bf16x8*)(Kb + krow + col0);
        const bf16x8 k1 = *(const bf16x8*)(Kb + krow + col0 + 8);

        float p = 0.f;
        #pragma unroll
        for (int i = 0; i < 8; ++i)
            p += bf2f((unsigned short)q0[i]) * bf2f((unsigned short)k0[i]);
        #pragma unroll
        for (int i = 0; i < 8; ++i)
            p += bf2f((unsigned short)q1[i]) * bf2f((unsigned short)k1[i]);

        p += __shfl_xor(p, 1, 64);
        p += __shfl_xor(p, 2, 64);
        const float logit = (p + bf2f(s_S2row[h * HD + rel_d])) * 0.125f;

        float mx = logit;
        #pragma unroll
        for (int m = 4; m < 64; m <<= 1) mx = fmaxf(mx, __shfl_xor(mx, m, 64));
        const float ex = __expf(logit - mx);
        float s = ex;
        #pragma unroll
        for (int m = 4; m < 64; m <<= 1) s += __shfl_xor(s, m, 64);
        if (c == 0) s_attn[h][d] = ex / s;
    }
    __syncthreads();

    if (t < NHEAD * 16) {
        const int h    = t >> 4;
        const int cc   = t & 15;
        const int col0 = h * HD + cc * 4;
        f32x4 acc = (f32x4){0.f, 0.f, 0.f, 0.f};
        #pragma unroll
        for (int d2 = 0; d2 < DEG; ++d2) {
            const float aw = s_attn[h][d2];
            const ushort4 v4 = *(const ushort4*)(Vb + (size_t)(b * NN + s_src[d2]) * HH + col0);
            const ushort4 e4 = *(const ushort4*)(Evb + (size_t)s_rel[d2] * HH + col0);
            acc[0] += aw * (bf2f(v4.x) + bf2f(e4.x));
            acc[1] += aw * (bf2f(v4.y) + bf2f(e4.y));
            acc[2] += aw * (bf2f(v4.z) + bf2f(e4.z));
            acc[3] += aw * (bf2f(v4.w) + bf2f(e4.w));
        }
        *(f32x4*)(out + (size_t)seg * HH + col0) = acc;
    }
}

// ---------------------------------------------------------------------------
extern "C" void kernel_launch(void* const* d_in, const int* in_sizes, int n_in,
                              void* d_out, int out_size, void* d_ws, size_t ws_size,
                              hipStream_t stream)
{
    const float* X  = (const float*)d_in[0];
    const int* eidx = (const int*)d_in[1];
    const float* Wq = (const float*)d_in[2];
    const float* bq = (const float*)d_in[3];
    const float* Wk = (const float*)d_in[4];
    const float* bk = (const float*)d_in[5];
    const float* Wv = (const float*)d_in[6];
    const float* bv = (const float*)d_in[7];
    const float* Ek = (const float*)d_in[8];
    const float* Ev = (const float*)d_in[9];
    float* out = (float*)d_out;

    // workspace layout (16B-aligned slices), total ~66.7 MB
    char* ws = (char*)d_ws;
    unsigned short* Qb  = (unsigned short*)ws;                 // 12582912 B
    unsigned short* Kb  = (unsigned short*)(ws + 12582912);    // 12582912 B
    unsigned short* Vb  = (unsigned short*)(ws + 25165824);    // 12582912 B
    unsigned short* Xb  = (unsigned short*)(ws + 37748736);    // 12582912 B
    unsigned short* Wb  = (unsigned short*)(ws + 50331648);    //  3538944 B
    float* biasb        = (float*)(ws + 53870592);             //     9216 B
    unsigned short* S2b = (unsigned short*)(ws + 53879808);    // 12582912 B
    unsigned short* Ekb = (unsigned short*)(ws + 66462720);    //    98304 B
    unsigned short* Evb = (unsigned short*)(ws + 66561024);    //    98304 B

    convert_x<<<3072, 256, 0, stream>>>(X, Xb);
    convert_w<<<864, 256, 0, stream>>>(Wq, Wk, Wv, bq, bk, bv, Wb, biasb);
    convert_e<<<48, 256, 0, stream>>>(Ek, Ev, Ekb, Evb);

    dim3 g(NOUT / 128, MTOT / 128);      // 18 x 64
    qkv_mfma<<<g, 256, 0, stream>>>(Xb, Wb, biasb, Qb, Kb, Vb);

    s2_kernel<<<dim3(128, NHEAD), 256, 0, stream>>>(Qb, Ekb, S2b);

    attn_kernel<<<MTOT, 256, 0, stream>>>(Qb, Kb, Vb, S2b, Evb, eidx, out);
}